// Round 1
// baseline (685.586 us; speedup 1.0000x reference)
//
#include <hip/hip_runtime.h>

// B=4096, F=128, E=128, NS=10
//   out[b] = relu(concat(features[nodes[b]], mean_k features[neigh_idx[b,k]]) @ weight[b])
// weight: [4096,256,128] f32 = 512 MiB, read exactly once -> HBM-bound, floor ~85us.
//
// This revision: BPB=4 batch items per block (1024 blocks, 4/CU, all co-resident).
//  - all indices for the block scalar-loaded at prologue (uniform -> SGPRs)
//  - next-b feature gathers ISSUED under current-b weight stream (summed later)
//  - weight prefetch pipeline never drains across b-boundaries: chunk 3 of item i
//    prefetches chunk 0 of item i+1 -> one contiguous 512 KB nontemporal stream/block.

constexpr int FEAT  = 128;
constexpr int EMBED = 128;
constexpr int NSAMP = 10;
constexpr int TWOF  = 2 * FEAT;
constexpr int BPB   = 4;                    // batch items per block
constexpr int WV4   = TWOF * EMBED / 4;     // v4f elements per weight tile (8192)

// Native clang vector type: __builtin_nontemporal_load requires it.
typedef float v4f __attribute__((ext_vector_type(4)));

__global__ __launch_bounds__(256) void encoder_kernel(
    const float* __restrict__ features,
    const float* __restrict__ weight,
    const int*   __restrict__ nodes,
    const int*   __restrict__ neigh_idx,
    float*       __restrict__ out,
    const int    batch)
{
    const int t    = threadIdx.x;
    const int quad = t & 31;   // output quad (4 consecutive embed cols)
    const int seg  = t >> 5;   // row segment: rows seg*32 .. seg*32+31
    const int b0   = blockIdx.x * BPB;
    if (b0 >= batch) return;   // uniform

    __shared__ float c[2][TWOF];           // double-buffered combined input vector
    __shared__ float partial[8 * 128];     // [seg][embed] 4 KB

    // ---- All indices for this block's BPB items: uniform -> scalar loads ----
    int nd[BPB];
    int ni[BPB][NSAMP];
#pragma unroll
    for (int i = 0; i < BPB; ++i) {
        const int bb = (b0 + i < batch) ? (b0 + i) : (batch - 1);
        nd[i] = nodes[bb];
#pragma unroll
        for (int k = 0; k < NSAMP; ++k) ni[i][k] = neigh_idx[bb * NSAMP + k];
    }

    const int f = t - FEAT;    // valid when t >= FEAT

    // ---- Gather item 0 (dependent-load latency exposed once per block) ----
    float g;
    if (t < FEAT) {
        g = features[(size_t)nd[0] * FEAT + t];
    } else {
        float s = 0.f;
#pragma unroll
        for (int k = 0; k < NSAMP; ++k)
            s += features[(size_t)ni[0][k] * FEAT + f];
        g = s * (1.0f / NSAMP);
    }

    // ---- Per-thread weight tile pointer (advances by WV4 per item) ----
    const v4f* wp = (const v4f*)weight + (size_t)b0 * WV4
                  + (size_t)seg * 32 * 32 + quad;

    // ---- Prefetch chunk 0 of item 0 ----
    v4f w[8];
#pragma unroll
    for (int j = 0; j < 8; ++j)
        w[j] = __builtin_nontemporal_load(wp + j * 32);

    int buf = 0;
    c[buf][t] = g;
    __syncthreads();

    for (int i = 0; i < BPB; ++i) {
        const int b = b0 + i;
        if (b >= batch) break;                              // uniform
        const bool haveNext = (i + 1 < BPB) && (b + 1 < batch);

        float accx = 0.f, accy = 0.f, accz = 0.f, accw = 0.f;
        float rself;
        float r[NSAMP];

#pragma unroll
        for (int chunk = 0; chunk < 4; ++chunk) {
            const bool pf = (chunk < 3) || haveNext;
            // chunks 1..3 of this item, then chunk 0 of the NEXT item:
            const v4f* src = (chunk < 3) ? (wp + (chunk + 1) * 8 * 32)
                                         : (wp + WV4);
            v4f wn[8];
            if (pf) {
#pragma unroll
                for (int j = 0; j < 8; ++j)
                    wn[j] = __builtin_nontemporal_load(src + j * 32);
            }

            if (chunk == 0 && haveNext) {
                // Issue next-item gather loads now; sum AFTER the chunk loop so
                // their latency hides under this item's weight stream.
                if (t < FEAT) {
                    rself = features[(size_t)nd[i + 1] * FEAT + t];
                } else {
#pragma unroll
                    for (int k = 0; k < NSAMP; ++k)
                        r[k] = features[(size_t)ni[i + 1][k] * FEAT + f];
                }
            }

            const int base = seg * 32 + chunk * 8;
#pragma unroll
            for (int j = 0; j < 8; ++j) {
                const float ci = c[buf][base + j];
                accx = fmaf(ci, w[j].x, accx);
                accy = fmaf(ci, w[j].y, accy);
                accz = fmaf(ci, w[j].z, accz);
                accw = fmaf(ci, w[j].w, accw);
            }
            if (pf) {
#pragma unroll
                for (int j = 0; j < 8; ++j) w[j] = wn[j];
            }
        }

        // partial[seg][quad*4 + 0..3]
        float* p = &partial[seg * 128 + quad * 4];
        p[0] = accx; p[1] = accy; p[2] = accz; p[3] = accw;

        if (haveNext) {
            float gnext;
            if (t < FEAT) {
                gnext = rself;
            } else {
                float s = 0.f;
#pragma unroll
                for (int k = 0; k < NSAMP; ++k) s += r[k];
                gnext = s * (1.0f / NSAMP);
            }
            c[buf ^ 1][t] = gnext;
        }
        __syncthreads();

        // ---- Reduce 8 segments, ReLU, coalesced store ----
        if (t < EMBED) {
            float s = 0.f;
#pragma unroll
            for (int sgi = 0; sgi < 8; ++sgi)
                s += partial[sgi * 128 + t];
            out[(size_t)b * EMBED + t] = fmaxf(s, 0.f);
        }

        buf ^= 1;
        wp += WV4;
        __syncthreads();   // protect partial/c reuse before next item
    }
}

extern "C" void kernel_launch(void* const* d_in, const int* in_sizes, int n_in,
                              void* d_out, int out_size, void* d_ws, size_t ws_size,
                              hipStream_t stream) {
    const float* features = (const float*)d_in[0];   // [100000,128] f32
    const float* weight   = (const float*)d_in[1];   // [4096,256,128] f32
    const int*   nodes    = (const int*)d_in[2];     // [4096] i32
    const int*   neigh    = (const int*)d_in[3];     // [4096,10] i32
    float*       outp     = (float*)d_out;           // [4096,128] f32

    const int batch = in_sizes[2];  // 4096
    const int grid  = (batch + BPB - 1) / BPB;
    encoder_kernel<<<grid, 256, 0, stream>>>(features, weight, nodes, neigh, outp, batch);
}